// Round 1
// baseline (862.209 us; speedup 1.0000x reference)
//
#include <hip/hip_runtime.h>
#include <math.h>

#define NPB 131072          // pixels per batch element: 4096*32
#define NOUT 80             // 64 trans + 8 gate + 8 attn
#define LRELU_SLOPE 0.2f
#define EPSV 1e-6f

// ---- pre-pass: concat+transpose the three 1x1-conv weights into WT[c][o] ----
__global__ __launch_bounds__(256) void wt_kernel(
    const float* __restrict__ w_trans,   // [64,128]
    const float* __restrict__ w_gate1,   // [8,128]
    const float* __restrict__ w_attn1,   // [8,128]
    float* __restrict__ WT)              // [128][80]
{
    int i = blockIdx.x * 256 + threadIdx.x;
    if (i >= 128 * NOUT) return;
    int c = i / NOUT;
    int o = i - c * NOUT;
    float v;
    if (o < 64)      v = w_trans[o * 128 + c];
    else if (o < 72) v = w_gate1[(o - 64) * 128 + c];
    else             v = w_attn1[(o - 72) * 128 + c];
    WT[i] = v;
}

// ---- main fused kernel: one thread = one pixel (b,n,k); wave = 2 groups ----
__global__ __launch_bounds__(256, 4) void gsl_kernel(
    const float* __restrict__ x,         // [8,128,4096,32]
    const float* __restrict__ WT,        // [128][80] in d_ws
    const float* __restrict__ g_trans, const float* __restrict__ b_trans,
    const float* __restrict__ g_gate,  const float* __restrict__ b_gate,
    const float* __restrict__ w_gate2, const float* __restrict__ b_gate2,
    const float* __restrict__ g_attn,  const float* __restrict__ b_attn,
    const float* __restrict__ w_attn2, const float* __restrict__ b_attn2,
    const float* __restrict__ agg_alpha,
    float* __restrict__ out0,            // [8,64,4096]
    float* __restrict__ outg)            // [8,1,4096,32]
{
    const int tid = threadIdx.x;
    const size_t p = (size_t)blockIdx.x * 256 + tid;   // global pixel
    const int b   = (int)(p >> 17);                    // p / 131072
    const int pin = (int)(p & (NPB - 1));
    const int n   = pin >> 5;

    const float* xp = x + (size_t)b * 128 * NPB + pin;

    float acc[NOUT];
#pragma unroll
    for (int o = 0; o < NOUT; ++o) acc[o] = 0.f;

    // GEMM part: acc[o] = sum_c WT[c][o] * x[c][pixel]
    // WT reads are wave-uniform -> SGPR loads; x reads coalesced (lane=pixel).
#pragma unroll 1
    for (int c0 = 0; c0 < 128; c0 += 8) {
        float xv[8];
#pragma unroll
        for (int i = 0; i < 8; ++i)
            xv[i] = xp[(size_t)(c0 + i) * NPB];
#pragma unroll
        for (int i = 0; i < 8; ++i) {
            const float* wc = WT + (size_t)(c0 + i) * NOUT;
#pragma unroll
            for (int o = 0; o < NOUT; ++o)
                acc[o] = fmaf(wc[o], xv[i], acc[o]);
        }
    }

    // ---- per-pixel heads (all data thread-local) ----
    float gl = b_gate2[0];
#pragma unroll
    for (int h = 0; h < 8; ++h) {
        float v = fmaf(acc[64 + h], g_gate[h], b_gate[h]);
        v = (v >= 0.f) ? v : LRELU_SLOPE * v;
        gl = fmaf(w_gate2[h], v, gl);
    }
    float al = b_attn2[0];
#pragma unroll
    for (int h = 0; h < 8; ++h) {
        float v = fmaf(acc[72 + h], g_attn[h], b_attn[h]);
        v = (v >= 0.f) ? v : LRELU_SLOPE * v;
        al = fmaf(w_attn2[h], v, al);
    }
    outg[p] = gl;   // gate_logits output (coalesced)

    // trans_feat = lrelu(affine(acc[0..63])) -- reuse acc registers
#pragma unroll
    for (int o = 0; o < 64; ++o) {
        float v = fmaf(acc[o], g_trans[o], b_trans[o]);
        acc[o] = (v >= 0.f) ? v : LRELU_SLOPE * v;
    }

    // ---- group (K=32) softmax with hard mask + renorm; group = 32 lanes ----
    float m = al;
#pragma unroll
    for (int s = 1; s < 32; s <<= 1) m = fmaxf(m, __shfl_xor(m, s, 32));
    float e = expf(al - m);
    float s1 = e;
#pragma unroll
    for (int s = 1; s < 32; s <<= 1) s1 += __shfl_xor(s1, s, 32);
    float w0 = e / s1;                       // softmax weight (unmasked)
    float wm = (gl >= 0.f) ? w0 : 0.f;       // deterministic gumbel mask (eval)
    float s2 = wm;
#pragma unroll
    for (int s = 1; s < 32; s <<= 1) s2 += __shfl_xor(s2, s, 32);
    const float wgt = wm / (s2 + EPSV);

    const float alpha = 1.f / (1.f + expf(-agg_alpha[0]));
    const float beta  = 1.f - alpha;

    const int lk = tid & 31;                 // lane-in-group == k
    float* outp = out0 + ((size_t)b * 64) * 4096 + n;

    // out[o,n] = alpha * sum_k t*wgt + beta * max_k t
#pragma unroll
    for (int o = 0; o < 64; ++o) {
        float sv = acc[o] * wgt;
        float mv = acc[o];
#pragma unroll
        for (int s = 1; s < 32; s <<= 1) {
            sv += __shfl_xor(sv, s, 32);
            mv = fmaxf(mv, __shfl_xor(mv, s, 32));
        }
        if (lk == (o & 31))                  // each lane writes o=lk and o=lk+32
            outp[(size_t)o * 4096] = fmaf(alpha, sv, beta * mv);
    }
}

extern "C" void kernel_launch(void* const* d_in, const int* in_sizes, int n_in,
                              void* d_out, int out_size, void* d_ws, size_t ws_size,
                              hipStream_t stream) {
    const float* x        = (const float*)d_in[0];
    const float* w_trans  = (const float*)d_in[1];
    const float* g_trans  = (const float*)d_in[2];
    const float* b_trans  = (const float*)d_in[3];
    const float* w_gate1  = (const float*)d_in[4];
    const float* g_gate   = (const float*)d_in[5];
    const float* b_gate   = (const float*)d_in[6];
    const float* w_gate2  = (const float*)d_in[7];
    const float* b_gate2  = (const float*)d_in[8];
    const float* w_attn1  = (const float*)d_in[9];
    const float* g_attn   = (const float*)d_in[10];
    const float* b_attn   = (const float*)d_in[11];
    const float* w_attn2  = (const float*)d_in[12];
    const float* b_attn2  = (const float*)d_in[13];
    const float* agg_alpha= (const float*)d_in[14];

    float* out0 = (float*)d_out;                       // [8,64,4096]
    float* outg = (float*)d_out + (size_t)8*64*4096;   // [8,1,4096,32]
    float* WT   = (float*)d_ws;                        // [128][80]

    wt_kernel<<<(128*NOUT + 255)/256, 256, 0, stream>>>(w_trans, w_gate1, w_attn1, WT);

    const int npix = 8 * NPB;                          // 1,048,576
    gsl_kernel<<<npix/256, 256, 0, stream>>>(
        x, WT, g_trans, b_trans, g_gate, b_gate, w_gate2, b_gate2,
        g_attn, b_attn, w_attn2, b_attn2, agg_alpha, out0, outg);
}